// Round 5
// baseline (82.664 us; speedup 1.0000x reference)
//
#include <hip/hip_runtime.h>
#include <math.h>

// Problem constants
#define BS 8
#define T  4096
#define D  257
#define SD 1028                        // 4 * 257 floats per t-row
#define K  (T * D)                     // 1,052,672 positions per batch
#define NACC 24                        // 4 pp + 4 gg + 16 pg
#define BPB 256                        // blocks per batch
#define NBLK (BS * BPB)                // 2048
#define CHUNK 4112                     // K / BPB positions = 16 full t-rows
#define NACC 24

__global__ __launch_bounds__(256) void zero_ws_kernel(float* ws) {
    int i = blockIdx.x * blockDim.x + threadIdx.x;
    if (i < BS * NACC) ws[i] = 0.0f;
}

// One position: read p0..p3 / g0..g3 (stride D within the t-row), 24 FMAs.
// ALL loads non-temporal: bypass/evict-first cache policy so the whole stream
// is served by HBM instead of the (slow) ~50%-hit MALL mixed path.
__device__ __forceinline__ void process_pos(const float* __restrict__ Pb,
                                            const float* __restrict__ Gb,
                                            int i, float* acc) {
    const int t = i / D;               // magic-mul division
    const int d = i - t * D;
    const float* p = Pb + (size_t)t * SD + d;
    const float* g = Gb + (size_t)t * SD + d;
    const float p0 = __builtin_nontemporal_load(p);
    const float p1 = __builtin_nontemporal_load(p + D);
    const float p2 = __builtin_nontemporal_load(p + 2 * D);
    const float p3 = __builtin_nontemporal_load(p + 3 * D);
    const float g0 = __builtin_nontemporal_load(g);
    const float g1 = __builtin_nontemporal_load(g + D);
    const float g2 = __builtin_nontemporal_load(g + 2 * D);
    const float g3 = __builtin_nontemporal_load(g + 3 * D);
    acc[0] = fmaf(p0, p0, acc[0]);  acc[1] = fmaf(p1, p1, acc[1]);
    acc[2] = fmaf(p2, p2, acc[2]);  acc[3] = fmaf(p3, p3, acc[3]);
    acc[4] = fmaf(g0, g0, acc[4]);  acc[5] = fmaf(g1, g1, acc[5]);
    acc[6] = fmaf(g2, g2, acc[6]);  acc[7] = fmaf(g3, g3, acc[7]);
    acc[ 8] = fmaf(p0, g0, acc[ 8]); acc[ 9] = fmaf(p0, g1, acc[ 9]);
    acc[10] = fmaf(p0, g2, acc[10]); acc[11] = fmaf(p0, g3, acc[11]);
    acc[12] = fmaf(p1, g0, acc[12]); acc[13] = fmaf(p1, g1, acc[13]);
    acc[14] = fmaf(p1, g2, acc[14]); acc[15] = fmaf(p1, g3, acc[15]);
    acc[16] = fmaf(p2, g0, acc[16]); acc[17] = fmaf(p2, g1, acc[17]);
    acc[18] = fmaf(p2, g2, acc[18]); acc[19] = fmaf(p2, g3, acc[19]);
    acc[20] = fmaf(p3, g0, acc[20]); acc[21] = fmaf(p3, g1, acc[21]);
    acc[22] = fmaf(p3, g2, acc[22]); acc[23] = fmaf(p3, g3, acc[23]);
}

// Each block owns ONE contiguous 16-t-row chunk (2 x 16.4 KB sequential
// windows in P and G) -> long-lived forward DRAM streams.
// DIRECT=1: per-block partials to ws[block*24+k]; DIRECT=0: atomics.
template <int DIRECT>
__global__ __launch_bounds__(256) void partial_kernel(const float* __restrict__ P,
                                                      const float* __restrict__ G,
                                                      float* __restrict__ ws) {
    const int tid  = threadIdx.x;
    const int lane = tid & 63;
    const int wv   = tid >> 6;
    const int b    = blockIdx.x >> 8;          // batch
    const int c    = blockIdx.x & (BPB - 1);   // chunk within batch

    const float* __restrict__ Pb = P + (size_t)b * T * SD;
    const float* __restrict__ Gb = G + (size_t)b * T * SD;

    float acc[NACC];
    #pragma unroll
    for (int k = 0; k < NACC; ++k) acc[k] = 0.0f;

    const int base = c * CHUNK;
    #pragma unroll 2
    for (int it = 0; it < CHUNK / 256; ++it)   // 16 iterations, exact fit
        process_pos(Pb, Gb, base + it * 256 + tid, acc);

    // block reduction: wave shuffle -> LDS -> 24 values
    __shared__ float sm[4][NACC];
    #pragma unroll
    for (int k = 0; k < NACC; ++k) {
        float v = acc[k];
        #pragma unroll
        for (int o = 32; o > 0; o >>= 1) v += __shfl_down(v, o, 64);
        if (lane == 0) sm[wv][k] = v;
    }
    __syncthreads();
    if (tid < NACC) {
        float v = sm[0][tid] + sm[1][tid] + sm[2][tid] + sm[3][tid];
        if (DIRECT) ws[blockIdx.x * NACC + tid] = v;
        else        atomicAdd(&ws[b * NACC + tid], v);
    }
}

__device__ __forceinline__ float greedy_total(const float* w8x24 /* [8][24] */) {
    float total = 0.f;
    for (int b = 0; b < BS; ++b) {
        const float* w = w8x24 + b * NACC;
        float dist[16];
        for (int s = 0; s < 4; ++s)
            for (int t = 0; t < 4; ++t) {
                float d2 = w[s] + w[4 + t] - 2.f * w[8 + s * 4 + t];
                dist[s * 4 + t] = sqrtf(fmaxf(d2, 0.f));
            }
        bool rdone[4] = {false, false, false, false};
        bool cdone[4] = {false, false, false, false};
        for (int it = 0; it < 4; ++it) {
            float best = INFINITY; int br = 0, bc = 0;
            bool found = false;
            for (int s = 0; s < 4; ++s) {
                if (rdone[s]) continue;
                for (int t = 0; t < 4; ++t) {
                    if (cdone[t]) continue;
                    float v = dist[s * 4 + t];
                    if (!found || v < best) { best = v; br = s; bc = t; found = true; }
                }
            }
            total += best;
            rdone[br] = true; cdone[bc] = true;
        }
    }
    return total * 0.125f;
}

// DIRECT=1 path: slot (b,k) lives at ws[((b<<8)|j)*24+k], j in [0,BPB).
__global__ __launch_bounds__(256) void finalize_direct_kernel(const float* __restrict__ ws,
                                                              float* __restrict__ out) {
    __shared__ float wsm[BS * NACC];
    const int t = threadIdx.x;
    if (t < BS * NACC) {
        const int b = t / NACC, k = t - b * NACC;
        float v = 0.f;
        for (int j = 0; j < BPB; ++j)
            v += ws[(size_t)((b << 8) | j) * NACC + k];
        wsm[t] = v;
    }
    __syncthreads();
    if (t == 0) *out = greedy_total(wsm);
}

__global__ void finalize_atomic_kernel(const float* __restrict__ ws, float* __restrict__ out) {
    if (threadIdx.x != 0 || blockIdx.x != 0) return;
    *out = greedy_total(ws);
}

extern "C" void kernel_launch(void* const* d_in, const int* in_sizes, int n_in,
                              void* d_out, int out_size, void* d_ws, size_t ws_size,
                              hipStream_t stream) {
    const float* P = (const float*)d_in[0];
    const float* G = (const float*)d_in[1];
    float* out = (float*)d_out;
    float* ws  = (float*)d_ws;

    if (ws_size >= (size_t)NBLK * NACC * sizeof(float)) {
        partial_kernel<1><<<NBLK, 256, 0, stream>>>(P, G, ws);
        finalize_direct_kernel<<<1, 256, 0, stream>>>(ws, out);
    } else {
        zero_ws_kernel<<<1, 256, 0, stream>>>(ws);
        partial_kernel<0><<<NBLK, 256, 0, stream>>>(P, G, ws);
        finalize_atomic_kernel<<<1, 64, 0, stream>>>(ws, out);
    }
}

// Round 6
// 75.338 us; speedup vs baseline: 1.0972x; 1.0972x over previous
//
#include <hip/hip_runtime.h>
#include <math.h>

// Problem constants
#define BS 8
#define T  4096
#define D  257
#define SD 1028                        // 4*257 floats per t-row (4112 B, 16B-aligned)
#define NACC 24                        // 4 pp + 4 gg + 16 pg
#define RPB 32                         // t-rows per block (8 per wave)
#define CPB 128                        // chunks (blocks) per batch: 4096/32
#define NBLK (BS * CPB)                // 1024

typedef float v4f __attribute__((ext_vector_type(4)));

__global__ __launch_bounds__(256) void zero_ws_kernel(float* ws) {
    int i = blockIdx.x * blockDim.x + threadIdx.x;
    if (i < BS * NACC) ws[i] = 0.0f;
}

// Issue 8 global_load_dwordx4 (one float4 per source row of P and G, same
// d-grid). Rows s=1..3 are 4B-aligned only — CDNA4 HW supports unaligned
// global loads; inline asm guarantees dwordx4 is emitted. offset: immediates
// are s*257 floats = s*1028 bytes. NO wait here — caller pipelines.
__device__ __forceinline__ void issue8(const float* pp, const float* gg,
                                       v4f& p0, v4f& p1, v4f& p2, v4f& p3,
                                       v4f& g0, v4f& g1, v4f& g2, v4f& g3) {
    asm volatile(
        "global_load_dwordx4 %0, %8, off\n\t"
        "global_load_dwordx4 %1, %8, off offset:1028\n\t"
        "global_load_dwordx4 %2, %8, off offset:2056\n\t"
        "global_load_dwordx4 %3, %8, off offset:3084\n\t"
        "global_load_dwordx4 %4, %9, off\n\t"
        "global_load_dwordx4 %5, %9, off offset:1028\n\t"
        "global_load_dwordx4 %6, %9, off offset:2056\n\t"
        "global_load_dwordx4 %7, %9, off offset:3084"
        : "=&v"(p0), "=&v"(p1), "=&v"(p2), "=&v"(p3),
          "=&v"(g0), "=&v"(g1), "=&v"(g2), "=&v"(g3)
        : "v"(pp), "v"(gg));
}

// Counted waits; sched_barrier stops the compiler hoisting dependent FMAs
// above the waitcnt (guide rule #18).
#define WAIT8 do { asm volatile("s_waitcnt vmcnt(8)" ::: "memory"); \
                   __builtin_amdgcn_sched_barrier(0); } while (0)
#define WAIT0 do { asm volatile("s_waitcnt vmcnt(0)" ::: "memory"); \
                   __builtin_amdgcn_sched_barrier(0); } while (0)

__device__ __forceinline__ void consume8(const v4f& p0, const v4f& p1,
                                         const v4f& p2, const v4f& p3,
                                         const v4f& g0, const v4f& g1,
                                         const v4f& g2, const v4f& g3,
                                         float* acc) {
    #pragma unroll
    for (int e = 0; e < 4; ++e) {
        const float a0 = p0[e], a1 = p1[e], a2 = p2[e], a3 = p3[e];
        const float b0 = g0[e], b1 = g1[e], b2 = g2[e], b3 = g3[e];
        acc[0] = fmaf(a0, a0, acc[0]);  acc[1] = fmaf(a1, a1, acc[1]);
        acc[2] = fmaf(a2, a2, acc[2]);  acc[3] = fmaf(a3, a3, acc[3]);
        acc[4] = fmaf(b0, b0, acc[4]);  acc[5] = fmaf(b1, b1, acc[5]);
        acc[6] = fmaf(b2, b2, acc[6]);  acc[7] = fmaf(b3, b3, acc[7]);
        acc[ 8] = fmaf(a0, b0, acc[ 8]); acc[ 9] = fmaf(a0, b1, acc[ 9]);
        acc[10] = fmaf(a0, b2, acc[10]); acc[11] = fmaf(a0, b3, acc[11]);
        acc[12] = fmaf(a1, b0, acc[12]); acc[13] = fmaf(a1, b1, acc[13]);
        acc[14] = fmaf(a1, b2, acc[14]); acc[15] = fmaf(a1, b3, acc[15]);
        acc[16] = fmaf(a2, b0, acc[16]); acc[17] = fmaf(a2, b1, acc[17]);
        acc[18] = fmaf(a2, b2, acc[18]); acc[19] = fmaf(a2, b3, acc[19]);
        acc[20] = fmaf(a3, b0, acc[20]); acc[21] = fmaf(a3, b1, acc[21]);
        acc[22] = fmaf(a3, b2, acc[22]); acc[23] = fmaf(a3, b3, acc[23]);
    }
}

// DIRECT=1: per-block partials to ws[block*24+k]; DIRECT=0: atomics.
template <int DIRECT>
__global__ __launch_bounds__(256) void partial_kernel(const float* __restrict__ P,
                                                      const float* __restrict__ G,
                                                      float* __restrict__ ws) {
    const int tid  = threadIdx.x;
    const int lane = tid & 63;
    const int wv   = tid >> 6;
    const int b    = blockIdx.x >> 7;          // batch
    const int c    = blockIdx.x & (CPB - 1);   // chunk within batch

    const float* __restrict__ Pb = P + (size_t)b * T * SD;
    const float* __restrict__ Gb = G + (size_t)b * T * SD;

    float acc[NACC];
    #pragma unroll
    for (int k = 0; k < NACC; ++k) acc[k] = 0.0f;

    // Wave wv owns t-rows [rowbase, rowbase+8). Lane covers d = 4*lane..4*lane+3
    // of every row -> one wave-load = 1 KiB contiguous per row-operand.
    const int rowbase = c * RPB + wv * 8;
    const float* pa = Pb + (size_t)rowbase * SD + (lane << 2);
    const float* ga = Gb + (size_t)rowbase * SD + (lane << 2);

    v4f A0, A1, A2, A3, A4, A5, A6, A7;
    v4f B0, B1, B2, B3, B4, B5, B6, B7;

    // 2-deep pipeline over 8 rows: issue r+1 while consuming r.
    issue8(pa,      ga,      A0, A1, A2, A3, A4, A5, A6, A7);
    issue8(pa + SD, ga + SD, B0, B1, B2, B3, B4, B5, B6, B7);
    #pragma unroll
    for (int k = 0; k < 3; ++k) {
        WAIT8; consume8(A0, A1, A2, A3, A4, A5, A6, A7, acc);
        issue8(pa + (size_t)(2 + 2 * k) * SD, ga + (size_t)(2 + 2 * k) * SD,
               A0, A1, A2, A3, A4, A5, A6, A7);
        WAIT8; consume8(B0, B1, B2, B3, B4, B5, B6, B7, acc);
        issue8(pa + (size_t)(3 + 2 * k) * SD, ga + (size_t)(3 + 2 * k) * SD,
               B0, B1, B2, B3, B4, B5, B6, B7);
    }
    WAIT8; consume8(A0, A1, A2, A3, A4, A5, A6, A7, acc);
    WAIT0; consume8(B0, B1, B2, B3, B4, B5, B6, B7, acc);

    // d=256 tail: threads 0..31 each handle one of the block's 32 rows.
    if (tid < RPB) {
        const float* p = Pb + (size_t)(c * RPB + tid) * SD + 256;
        const float* g = Gb + (size_t)(c * RPB + tid) * SD + 256;
        const float a0 = p[0], a1 = p[D], a2 = p[2 * D], a3 = p[3 * D];
        const float b0 = g[0], b1 = g[D], b2 = g[2 * D], b3 = g[3 * D];
        acc[0] = fmaf(a0, a0, acc[0]);  acc[1] = fmaf(a1, a1, acc[1]);
        acc[2] = fmaf(a2, a2, acc[2]);  acc[3] = fmaf(a3, a3, acc[3]);
        acc[4] = fmaf(b0, b0, acc[4]);  acc[5] = fmaf(b1, b1, acc[5]);
        acc[6] = fmaf(b2, b2, acc[6]);  acc[7] = fmaf(b3, b3, acc[7]);
        acc[ 8] = fmaf(a0, b0, acc[ 8]); acc[ 9] = fmaf(a0, b1, acc[ 9]);
        acc[10] = fmaf(a0, b2, acc[10]); acc[11] = fmaf(a0, b3, acc[11]);
        acc[12] = fmaf(a1, b0, acc[12]); acc[13] = fmaf(a1, b1, acc[13]);
        acc[14] = fmaf(a1, b2, acc[14]); acc[15] = fmaf(a1, b3, acc[15]);
        acc[16] = fmaf(a2, b0, acc[16]); acc[17] = fmaf(a2, b1, acc[17]);
        acc[18] = fmaf(a2, b2, acc[18]); acc[19] = fmaf(a2, b3, acc[19]);
        acc[20] = fmaf(a3, b0, acc[20]); acc[21] = fmaf(a3, b1, acc[21]);
        acc[22] = fmaf(a3, b2, acc[22]); acc[23] = fmaf(a3, b3, acc[23]);
    }

    // block reduction: wave shuffle -> LDS -> 24 values
    __shared__ float sm[4][NACC];
    #pragma unroll
    for (int k = 0; k < NACC; ++k) {
        float v = acc[k];
        #pragma unroll
        for (int o = 32; o > 0; o >>= 1) v += __shfl_down(v, o, 64);
        if (lane == 0) sm[wv][k] = v;
    }
    __syncthreads();
    if (tid < NACC) {
        float v = sm[0][tid] + sm[1][tid] + sm[2][tid] + sm[3][tid];
        if (DIRECT) ws[blockIdx.x * NACC + tid] = v;
        else        atomicAdd(&ws[b * NACC + tid], v);
    }
}

__device__ __forceinline__ float greedy_total(const float* w8x24 /* [8][24] */) {
    float total = 0.f;
    for (int b = 0; b < BS; ++b) {
        const float* w = w8x24 + b * NACC;
        float dist[16];
        for (int s = 0; s < 4; ++s)
            for (int t = 0; t < 4; ++t) {
                float d2 = w[s] + w[4 + t] - 2.f * w[8 + s * 4 + t];
                dist[s * 4 + t] = sqrtf(fmaxf(d2, 0.f));
            }
        bool rdone[4] = {false, false, false, false};
        bool cdone[4] = {false, false, false, false};
        for (int it = 0; it < 4; ++it) {
            float best = INFINITY; int br = 0, bc = 0;
            bool found = false;
            for (int s = 0; s < 4; ++s) {
                if (rdone[s]) continue;
                for (int t = 0; t < 4; ++t) {
                    if (cdone[t]) continue;
                    float v = dist[s * 4 + t];
                    if (!found || v < best) { best = v; br = s; bc = t; found = true; }
                }
            }
            total += best;
            rdone[br] = true; cdone[bc] = true;
        }
    }
    return total * 0.125f;
}

// DIRECT=1 path: slot (b,k) lives at ws[(b*CPB+j)*24+k], j in [0,CPB).
__global__ __launch_bounds__(256) void finalize_direct_kernel(const float* __restrict__ ws,
                                                              float* __restrict__ out) {
    __shared__ float wsm[BS * NACC];
    const int t = threadIdx.x;
    if (t < BS * NACC) {
        const int b = t / NACC, k = t - b * NACC;
        float v = 0.f;
        for (int j = 0; j < CPB; ++j)
            v += ws[(size_t)(b * CPB + j) * NACC + k];
        wsm[t] = v;
    }
    __syncthreads();
    if (t == 0) *out = greedy_total(wsm);
}

__global__ void finalize_atomic_kernel(const float* __restrict__ ws, float* __restrict__ out) {
    if (threadIdx.x != 0 || blockIdx.x != 0) return;
    *out = greedy_total(ws);
}

extern "C" void kernel_launch(void* const* d_in, const int* in_sizes, int n_in,
                              void* d_out, int out_size, void* d_ws, size_t ws_size,
                              hipStream_t stream) {
    const float* P = (const float*)d_in[0];
    const float* G = (const float*)d_in[1];
    float* out = (float*)d_out;
    float* ws  = (float*)d_ws;

    if (ws_size >= (size_t)NBLK * NACC * sizeof(float)) {
        partial_kernel<1><<<NBLK, 256, 0, stream>>>(P, G, ws);
        finalize_direct_kernel<<<1, 256, 0, stream>>>(ws, out);
    } else {
        zero_ws_kernel<<<1, 256, 0, stream>>>(ws);
        partial_kernel<0><<<NBLK, 256, 0, stream>>>(P, G, ws);
        finalize_atomic_kernel<<<1, 64, 0, stream>>>(ws, out);
    }
}